// Round 6
// baseline (588.530 us; speedup 1.0000x reference)
//
#include <hip/hip_runtime.h>

// Committee vote histogram:
//   logits[m,b,c] = x[b,:] . W[m,:,c] + bias[m,c]
//   votes[m,b]    = argmax_c logits
//   out[b,c]      = #{ m : votes[m,b] == c }   (float32)
//
// B=65536, D=512, M=16, C=10.
// R6: identical to the proven R3 structure (64 rows/block, one model per
// wave, acc[10], 640-FMA unrolled chunk body, double-buffered LDS x tile)
// EXCEPT W is fetched through the VMEM pipe instead of the scalar pipe.
// R1-R5 all pinned VALU busy-time at ~80 us with 30-47% duty regardless of
// structure -> the invariant bottleneck is the scalar K$ path feeding W
// (32 B/cy/CU demand ~ K$ service rate, ~1.5 kq-groups of SGPR look-ahead).
// Dropping readfirstlane keeps W addresses divergent-looking -> the compiler
// emits global_load_dwordx4 (uniform address -> one broadcast L1 transaction)
// with deep VGPR-budget pipelining under vmcnt.

#define NB_ROWS 64
#define DDIM    512
#define NCLS    10
#define KCHUNK  64
#define NCHUNK  (DDIM / KCHUNK)   // 8

__global__ __launch_bounds__(1024, 4)
void committee_kernel(const float* __restrict__ x,
                      const float* __restrict__ W,
                      const float* __restrict__ bias,
                      float* __restrict__ out)
{
    // xs[buf][kq][row]: x[row][ch*64 + 4*kq .. +3]
    __shared__ float4 xs[2][16][65];
    __shared__ int ihist[NB_ROWS * NCLS];

    const int tid  = threadIdx.x;
    const int row0 = blockIdx.x * NB_ROWS;

    if (tid < NB_ROWS * NCLS) ihist[tid] = 0;

    // wave = model. INTENTIONALLY no readfirstlane: keep m "divergent" so W
    // reads stay on the VMEM pipe (VGPR addresses), not the scalar K$ pipe.
    const int m    = tid >> 6;
    const int lane = tid & 63;   // row within tile

    const float* wp = W + (size_t)m * DDIM * NCLS;

    float acc[NCLS];
#pragma unroll
    for (int c = 0; c < NCLS; ++c) acc[c] = bias[m * NCLS + c];

    // staging: thread t loads x[row0 + t/16][4*(t%16) .. +3] of each chunk
    const int srow = tid >> 4;   // 0..63
    const int skq  = tid & 15;   // 0..15
    const float* gsrc = x + (size_t)(row0 + srow) * DDIM + (skq << 2);

    // prologue: stage chunk 0 directly, issue load for chunk 1
    float4 pa = *reinterpret_cast<const float4*>(gsrc);
    xs[0][skq][srow] = pa;
    pa = *reinterpret_cast<const float4*>(gsrc + KCHUNK);

    for (int ch = 0; ch < NCHUNK; ++ch) {
        __syncthreads();           // prev readers of buf[cur^1] done;
        const int cur = ch & 1;    // buf[cur] writes visible

        if (ch + 1 < NCHUNK) {
            // write prefetched chunk ch+1, then issue load for ch+2
            xs[cur ^ 1][skq][srow] = pa;
            if (ch + 2 < NCHUNK) {
                pa = *reinterpret_cast<const float4*>(
                    gsrc + (size_t)(ch + 2) * KCHUNK);
            }
        }

#pragma unroll
        for (int kq = 0; kq < 16; ++kq) {
            const float4 xv = xs[cur][kq][lane];
            const float xarr[4] = {xv.x, xv.y, xv.z, xv.w};

            // 40 contiguous W floats for this kq, as 10 float4 VMEM loads
            // (wave-uniform address -> single 16B L1 transaction each).
            const float* wk = wp + (size_t)(ch * KCHUNK + (kq << 2)) * NCLS;
            float wq[40];
#pragma unroll
            for (int q = 0; q < 10; ++q) {
                const float4 wv = *reinterpret_cast<const float4*>(wk + (q << 2));
                wq[q * 4 + 0] = wv.x;
                wq[q * 4 + 1] = wv.y;
                wq[q * 4 + 2] = wv.z;
                wq[q * 4 + 3] = wv.w;
            }

#pragma unroll
            for (int j = 0; j < 4; ++j) {
                const float xj = xarr[j];
#pragma unroll
                for (int c = 0; c < NCLS; ++c)
                    acc[c] = fmaf(xj, wq[j * NCLS + c], acc[c]);
            }
        }
    }

    // argmax with first-occurrence-of-max semantics (strict >)
    int best = 0;
    float bv = acc[0];
#pragma unroll
    for (int c = 1; c < NCLS; ++c) {
        if (acc[c] > bv) { bv = acc[c]; best = c; }
    }

    atomicAdd(&ihist[lane * NCLS + best], 1);
    __syncthreads();

    if (tid < NB_ROWS * NCLS) {
        out[(size_t)row0 * NCLS + tid] = (float)ihist[tid];
    }
}

extern "C" void kernel_launch(void* const* d_in, const int* in_sizes, int n_in,
                              void* d_out, int out_size, void* d_ws, size_t ws_size,
                              hipStream_t stream) {
    const float* x  = (const float*)d_in[0];   // [65536, 512]
    const float* W  = (const float*)d_in[1];   // [16, 512, 10]
    const float* b  = (const float*)d_in[2];   // [16, 10]
    float* out      = (float*)d_out;           // [65536, 10]

    const int nblocks = 65536 / NB_ROWS;       // 1024
    committee_kernel<<<nblocks, 1024, 0, stream>>>(x, W, b, out);
}

// Round 7
// 210.306 us; speedup vs baseline: 2.7984x; 2.7984x over previous
//
#include <hip/hip_runtime.h>

// Committee vote histogram:
//   logits[m,b,c] = x[b,:] . W[m,:,c] + bias[m,c]
//   votes[m,b]    = argmax_c logits
//   out[b,c]      = #{ m : votes[m,b] == c }   (float32)
//
// B=65536, D=512, M=16, C=10.
// R7: W delivered from LDS. R1-R6 showed every cache-fed W path stalls the
// VALU (scalar K$: 40-47% duty; VMEM L1/L2: 20%). Here each d-chunk of W for
// all 16 models (20 KB) is staged into LDS (double-buffered) by the whole
// block, then each wave reads its model's 40 floats/kq as 10 same-address
// broadcast ds_read_b128 (conflict-free) - a pipe the compiler schedules
// with fine-grained lgkmcnt. x tile staged as before. One barrier per chunk.
// W float4s are consumed immediately (static j/c decomposition) to keep live
// registers ~50 -> 64-VGPR / 2-blocks-per-CU target.

#define NB_ROWS 64
#define DDIM    512
#define NCLS    10
#define KCHUNK  32
#define NCHUNK  (DDIM / KCHUNK)      // 16
#define WCH4    80                   // float4 per model per chunk (320 floats)
#define WTOT4   (16 * WCH4)          // 1280 float4 per chunk (all models)

__global__ __launch_bounds__(1024, 8)
void committee_kernel(const float* __restrict__ x,
                      const float* __restrict__ W,
                      const float* __restrict__ bias,
                      float* __restrict__ out)
{
    // xs[buf][kq][row]: x[row][ch*32 + 4*kq .. +3]
    __shared__ float4 xs[2][8][65];
    // ws4[buf][m*80 + kq*10 + q]: W[m][ch*32 + ...] chunk, global layout
    __shared__ float4 ws4[2][WTOT4];
    __shared__ int ihist[NB_ROWS * NCLS];

    const int tid  = threadIdx.x;
    const int row0 = blockIdx.x * NB_ROWS;

    if (tid < NB_ROWS * NCLS) ihist[tid] = 0;

    const int m    = __builtin_amdgcn_readfirstlane(tid >> 6);  // wave = model
    const int lane = tid & 63;                                  // row in tile

    float acc[NCLS];
#pragma unroll
    for (int c = 0; c < NCLS; ++c) acc[c] = bias[m * NCLS + c];

    // ---- staging assignments ----
    // x: threads 0..511, one float4: row = tid>>3, kq = tid&7
    const int srow = tid >> 3;
    const int skq  = tid & 7;
    const float* gsrc = x + (size_t)(row0 + srow) * DDIM + (skq << 2);
    // W: all threads: float4 index i4 = tid (+1024 for tid<256)
    const float4* W4 = reinterpret_cast<const float4*>(W);
    const int i4a = tid;                 // < 1280 always
    const int i4b = tid + 1024;          // < 1280 only for tid < 256
    const int ma  = i4a / WCH4, oa = i4a % WCH4;   // model, offset
    const int mb  = i4b / WCH4, ob = i4b % WCH4;
    // global float4 index for chunk ch: m*1280 + ch*80 + off
    #define WGIDX(mm, ch, off) ((size_t)(mm) * 1280 + (size_t)(ch) * WCH4 + (off))

    // ---- prologue: stage chunk 0 directly ----
    if (tid < 512) xs[0][skq][srow] = *reinterpret_cast<const float4*>(gsrc);
    ws4[0][i4a] = W4[WGIDX(ma, 0, oa)];
    if (tid < 256) ws4[0][i4b] = W4[WGIDX(mb, 0, ob)];

    // prefetch chunk 1 into registers
    float4 px, pw0, pw1;
    if (tid < 512) px = *reinterpret_cast<const float4*>(gsrc + KCHUNK);
    pw0 = W4[WGIDX(ma, 1, oa)];
    if (tid < 256) pw1 = W4[WGIDX(mb, 1, ob)];

    for (int ch = 0; ch < NCHUNK; ++ch) {
        __syncthreads();           // prev readers of buf[cur^1] done;
        const int cur = ch & 1;    // buf[cur] writes visible

        if (ch + 1 < NCHUNK) {
            // write prefetched chunk ch+1, then issue loads for ch+2
            if (tid < 512) xs[cur ^ 1][skq][srow] = px;
            ws4[cur ^ 1][i4a] = pw0;
            if (tid < 256) ws4[cur ^ 1][i4b] = pw1;
            if (ch + 2 < NCHUNK) {
                if (tid < 512)
                    px = *reinterpret_cast<const float4*>(
                        gsrc + (size_t)(ch + 2) * KCHUNK);
                pw0 = W4[WGIDX(ma, ch + 2, oa)];
                if (tid < 256) pw1 = W4[WGIDX(mb, ch + 2, ob)];
            }
        }

#pragma unroll
        for (int kq = 0; kq < 8; ++kq) {
            const float4 xv = xs[cur][kq][lane];
            const float xarr[4] = {xv.x, xv.y, xv.z, xv.w};
#pragma unroll
            for (int q = 0; q < 10; ++q) {
                // broadcast read: all lanes same address -> no conflict
                const float4 wv = ws4[cur][m * WCH4 + kq * 10 + q];
                const float warr[4] = {wv.x, wv.y, wv.z, wv.w};
#pragma unroll
                for (int k = 0; k < 4; ++k) {
                    const int f = 4 * q + k;      // flat (j,c): f = j*10 + c
                    const int j = f / 10;
                    const int c = f % 10;
                    acc[c] = fmaf(xarr[j], warr[k], acc[c]);
                }
            }
        }
    }

    // argmax with first-occurrence-of-max semantics (strict >)
    int best = 0;
    float bv = acc[0];
#pragma unroll
    for (int c = 1; c < NCLS; ++c) {
        if (acc[c] > bv) { bv = acc[c]; best = c; }
    }

    atomicAdd(&ihist[lane * NCLS + best], 1);
    __syncthreads();

    if (tid < NB_ROWS * NCLS) {
        out[(size_t)row0 * NCLS + tid] = (float)ihist[tid];
    }
}

extern "C" void kernel_launch(void* const* d_in, const int* in_sizes, int n_in,
                              void* d_out, int out_size, void* d_ws, size_t ws_size,
                              hipStream_t stream) {
    const float* x  = (const float*)d_in[0];   // [65536, 512]
    const float* W  = (const float*)d_in[1];   // [16, 512, 10]
    const float* b  = (const float*)d_in[2];   // [16, 10]
    float* out      = (float*)d_out;           // [65536, 10]

    const int nblocks = 65536 / NB_ROWS;       // 1024
    committee_kernel<<<nblocks, 1024, 0, stream>>>(x, W, b, out);
}

// Round 8
// 207.412 us; speedup vs baseline: 2.8375x; 1.0140x over previous
//
#include <hip/hip_runtime.h>

// Committee vote histogram:
//   logits[m,b,c] = x[b,:] . W[m,:,c] + bias[m,c]
//   votes[m,b]    = argmax_c logits
//   out[b,c]      = #{ m : votes[m,b] == c }   (float32)
//
// B=65536, D=512, M=16, C=10.
// R8: W delivered from LDS (R7 proved the pipe: duty 40->55%), with the R7
// spill fixed: (1) launch_bounds(1024,4) -> 128-VGPR cap, (2) W staged by
// async global_load_lds (width 16) -> no W prefetch registers, no W LDS-write
// phase. Wave m stages model m's 80-float4 chunk slice at linear LDS dest
// (wave-uniform base + lane*16). x keeps the proven register-staging path.
// One barrier per chunk; the barrier's vmcnt(0) drain makes staged W visible.

#define NB_ROWS 64
#define DDIM    512
#define NCLS    10
#define KCHUNK  32
#define NCHUNK  (DDIM / KCHUNK)      // 16
#define WCH4    80                   // float4 per model per chunk (320 floats)
#define WTOT4   (16 * WCH4)          // 1280 float4 per chunk (all models)

typedef __attribute__((address_space(1))) const void global_cv;
typedef __attribute__((address_space(3))) void lds_v;

__global__ __launch_bounds__(1024, 4)
void committee_kernel(const float* __restrict__ x,
                      const float* __restrict__ W,
                      const float* __restrict__ bias,
                      float* __restrict__ out)
{
    // xs[buf][kq][row]: x[row][ch*32 + 4*kq .. +3]
    __shared__ float4 xs[2][8][65];
    // ws4[buf][m*80 + kq*10 + q]: W[m] chunk, linear per model
    __shared__ float4 ws4[2][WTOT4];
    __shared__ int ihist[NB_ROWS * NCLS];

    const int tid  = threadIdx.x;
    const int row0 = blockIdx.x * NB_ROWS;

    if (tid < NB_ROWS * NCLS) ihist[tid] = 0;

    const int m    = __builtin_amdgcn_readfirstlane(tid >> 6);  // wave = model
    const int lane = tid & 63;                                  // row in tile

    float acc[NCLS];
#pragma unroll
    for (int c = 0; c < NCLS; ++c) acc[c] = bias[m * NCLS + c];

    // ---- x staging (register path): threads 0..511, one float4 per chunk
    const int srow = tid >> 3;   // 0..63
    const int skq  = tid & 7;    // 0..7
    const float* gsrc = x + (size_t)(row0 + srow) * DDIM + (skq << 2);

    // ---- W staging (async DMA): wave m stages model m's chunk slice.
    // chunk ch, float4 f in [0,80): global idx m*1280 + ch*80 + f,
    // LDS idx m*80 + f. Instr A: f = lane (all 64); instr B: f = 64+lane
    // (lanes 0..15). LDS dest = wave-uniform base + lane*16 (linear rule).
    const float4* W4  = reinterpret_cast<const float4*>(W);
    const float4* wgA = W4 + (size_t)m * 1280 + lane;
    const float4* wgB = W4 + (size_t)m * 1280 + 64 + lane;

    // ---- prologue: stage chunk 0 (x direct, W async), prefetch x of chunk 1
    float4 px;
    if (tid < 512) xs[0][skq][srow] = *reinterpret_cast<const float4*>(gsrc);
    __builtin_amdgcn_global_load_lds((global_cv*)wgA, (lds_v*)&ws4[0][m * WCH4],
                                     16, 0, 0);
    if (lane < 16)
        __builtin_amdgcn_global_load_lds((global_cv*)wgB,
                                         (lds_v*)&ws4[0][m * WCH4 + 64],
                                         16, 0, 0);
    if (tid < 512) px = *reinterpret_cast<const float4*>(gsrc + KCHUNK);

    for (int ch = 0; ch < NCHUNK; ++ch) {
        __syncthreads();           // drains vmcnt: staged W/x of buf[cur]
        const int cur = ch & 1;    // visible; prev readers of buf[cur^1] done

        if (ch + 1 < NCHUNK) {
            // issue async W stage for ch+1 (lands during this compute phase)
            __builtin_amdgcn_global_load_lds(
                (global_cv*)(wgA + (size_t)(ch + 1) * WCH4),
                (lds_v*)&ws4[cur ^ 1][m * WCH4], 16, 0, 0);
            if (lane < 16)
                __builtin_amdgcn_global_load_lds(
                    (global_cv*)(wgB + (size_t)(ch + 1) * WCH4),
                    (lds_v*)&ws4[cur ^ 1][m * WCH4 + 64], 16, 0, 0);
            // x: write prefetched chunk ch+1, issue load for ch+2
            if (tid < 512) {
                xs[cur ^ 1][skq][srow] = px;
                if (ch + 2 < NCHUNK)
                    px = *reinterpret_cast<const float4*>(
                        gsrc + (size_t)(ch + 2) * KCHUNK);
            }
        }

#pragma unroll
        for (int kq = 0; kq < 8; ++kq) {
            const float4 xv = xs[cur][kq][lane];
            const float xarr[4] = {xv.x, xv.y, xv.z, xv.w};
#pragma unroll
            for (int q = 0; q < 10; ++q) {
                // broadcast read: all lanes same address -> conflict-free
                const float4 wv = ws4[cur][m * WCH4 + kq * 10 + q];
                const float warr[4] = {wv.x, wv.y, wv.z, wv.w};
#pragma unroll
                for (int k = 0; k < 4; ++k) {
                    const int f = 4 * q + k;      // flat (j,c): f = j*10 + c
                    const int j = f / 10;
                    const int c = f % 10;
                    acc[c] = fmaf(xarr[j], warr[k], acc[c]);
                }
            }
        }
    }

    // argmax with first-occurrence-of-max semantics (strict >)
    int best = 0;
    float bv = acc[0];
#pragma unroll
    for (int c = 1; c < NCLS; ++c) {
        if (acc[c] > bv) { bv = acc[c]; best = c; }
    }

    atomicAdd(&ihist[lane * NCLS + best], 1);
    __syncthreads();

    if (tid < NB_ROWS * NCLS) {
        out[(size_t)row0 * NCLS + tid] = (float)ihist[tid];
    }
}

extern "C" void kernel_launch(void* const* d_in, const int* in_sizes, int n_in,
                              void* d_out, int out_size, void* d_ws, size_t ws_size,
                              hipStream_t stream) {
    const float* x  = (const float*)d_in[0];   // [65536, 512]
    const float* W  = (const float*)d_in[1];   // [16, 512, 10]
    const float* b  = (const float*)d_in[2];   // [16, 10]
    float* out      = (float*)d_out;           // [65536, 10]

    const int nblocks = 65536 / NB_ROWS;       // 1024
    committee_kernel<<<nblocks, 1024, 0, stream>>>(x, W, b, out);
}